// Round 8
// baseline (25.882 us; speedup 1.0000x reference)
//
#include <hip/hip_runtime.h>
#include <math.h>

namespace {
constexpr int kBatch = 65536;
constexpr int kSteps = 60;
constexpr int kNodes = 1024;                 // table nodes per step
constexpr float kInvDx = 64.0f;              // 1 / (16.0/1024)
constexpr float kDx    = 1.0f / 64.0f;

constexpr int kTiles = kSteps * kNodes / 16; // 3840 M-tiles of 16 nodes
constexpr int kBuildGrid = 480;              // 4 tile-iters per wave-pair

constexpr int kPitch = 136;                  // LDS W2 row pitch (shorts); 272B = 16*17 -> 16B aligned

constexpr float kDT        = 1.0f / 12.0f;
constexpr float kLam       = 0.01f;
constexpr float kTexp      = 5.0f;
constexpr float kPrincipal = 100.0f;
constexpr float kGmdb      = 100.0f;
constexpr float kFee       = 0.0196f;
}

typedef short short8 __attribute__((ext_vector_type(8)));
typedef float f32x4  __attribute__((ext_vector_type(4)));

// float -> bf16 bits, round-to-nearest-even (finite inputs only)
__device__ inline short f2bf(float f) {
    unsigned u = __builtin_bit_cast(unsigned, f);
    u += 0x7FFFu + ((u >> 16) & 1u);
    return (short)(u >> 16);
}

// MFMA table build.  Block = 256 = 4 waves: wave (mslot, nh).
// W2 is staged ONCE per block into LDS (coalesced float4 read, bf16,
// transposed [col][row], pitch 136) -> waves read B-fragments as short8
// ds_reads instead of 128 scattered 4B VMEM loads each.
// Table layout: float4 per (step, interval i): (delta_i, feepay_i,
// delta_{i+1}, feepay_{i+1}); node (s,n) stored to interval n (.xy) and
// interval n-1 (.zw) -> main does ONE aligned 16B gather per step.
__global__ __launch_bounds__(256) void va_build_table(
    const float* __restrict__ W1,   // [2,128]
    const float* __restrict__ b1,   // [128]
    const float* __restrict__ W2,   // [128,128] row-major (j, o)
    const float* __restrict__ b2,   // [128]
    const float* __restrict__ W3,   // [128]
    const float* __restrict__ b3,   // [1]
    float2* __restrict__ tab2)      // float2 view of the float4 table
{
    const int tid   = threadIdx.x;
    const int lane  = tid & 63;
    const int lo    = lane & 15;        // A-row / C-col within tile
    const int hi    = lane >> 4;        // k-block selector
    const int wv    = tid >> 6;
    const int mslot = wv >> 1;
    const int nh    = wv & 1;

    __shared__ unsigned short w2s[128 * kPitch];   // 34 KiB, bf16 [col][row]
    __shared__ float red[2][2][16][4];             // [mslot][nh][group][r]

    // ---- stage W2 into LDS: thread handles 16 groups of 4 consecutive o's
    #pragma unroll
    for (int i = 0; i < 16; ++i) {
        const int idx = tid * 4 + i * 1024;        // element index in [0,16384)
        const int j   = idx >> 7;                  // row
        const int o   = idx & 127;                 // col base
        const f32x4 v = *reinterpret_cast<const f32x4*>(W2 + idx);
        #pragma unroll
        for (int c = 0; c < 4; ++c)
            w2s[(o + c) * kPitch + j] = (unsigned short)f2bf(v[c]);
    }
    __syncthreads();

    // ---- per-wave state: B fragments from LDS + b2/W3 for our 64 cols
    short8 bfrag[4][4];                 // [nt][kc]
    float  b2v[4], w3v[4];
    #pragma unroll
    for (int nt = 0; nt < 4; ++nt) {
        const int col = nh * 64 + nt * 16 + lo;
        b2v[nt] = b2[col];
        w3v[nt] = W3[col];
        #pragma unroll
        for (int kc = 0; kc < 4; ++kc) {
            const int kb = kc * 32 + hi * 8;
            bfrag[nt][kc] = *reinterpret_cast<const short8*>(&w2s[col * kPitch + kb]);
        }
    }
    const float b3v = b3[0];

    for (int tile = blockIdx.x * 2 + mslot; tile < kTiles; tile += 2 * gridDim.x) {
        const int   s    = tile >> 6;               // 64 tiles per step
        const int   n0   = (tile & 63) << 4;
        const float t    = (float)s * kDT;
        const float spot = (float)(n0 + lo) * kDx;

        // ---- A fragments: h1 in MFMA A-layout (row=lo, k=kc*32+hi*8+e)
        short8 afrag[4];
        #pragma unroll
        for (int kc = 0; kc < 4; ++kc) {
            const int kb = kc * 32 + hi * 8;
            const f32x4* aw = reinterpret_cast<const f32x4*>(W1 + kb);        // W1[0][k]
            const f32x4* ap = reinterpret_cast<const f32x4*>(W1 + 128 + kb);  // W1[1][k]
            const f32x4* ab = reinterpret_cast<const f32x4*>(b1 + kb);
            const f32x4 a0 = aw[0], a1 = aw[1];
            const f32x4 p0 = ap[0], p1 = ap[1];
            const f32x4 c0 = ab[0], c1 = ab[1];
            short8 af;
            #pragma unroll
            for (int e = 0; e < 4; ++e) {
                float h = fmaxf(fmaf(spot, a0[e], fmaf(t, p0[e], c0[e])), 0.0f);
                af[e] = f2bf(h);
            }
            #pragma unroll
            for (int e = 0; e < 4; ++e) {
                float h = fmaxf(fmaf(spot, a1[e], fmaf(t, p1[e], c1[e])), 0.0f);
                af[4 + e] = f2bf(h);
            }
            afrag[kc] = af;
        }

        // ---- 16 MFMAs: acc[nt] covers C rows 4*hi+r, col nh*64+nt*16+lo
        f32x4 acc[4];
        #pragma unroll
        for (int nt = 0; nt < 4; ++nt) {
            f32x4 a = {b2v[nt], b2v[nt], b2v[nt], b2v[nt]};
            #pragma unroll
            for (int kc = 0; kc < 4; ++kc)
                a = __builtin_amdgcn_mfma_f32_16x16x32_bf16(afrag[kc], bfrag[nt][kc], a, 0, 0, 0);
            acc[nt] = a;
        }

        // ---- relu + W3 dot, butterfly over the 16-lane col group
        float part[4];
        #pragma unroll
        for (int r = 0; r < 4; ++r) {
            float p = 0.0f;
            #pragma unroll
            for (int nt = 0; nt < 4; ++nt)
                p = fmaf(fmaxf(acc[nt][r], 0.0f), w3v[nt], p);
            part[r] = p;
        }
        #pragma unroll
        for (int m = 1; m < 16; m <<= 1) {
            #pragma unroll
            for (int r = 0; r < 4; ++r)
                part[r] += __shfl_xor(part[r], m);
        }
        if (lo == 0) {
            #pragma unroll
            for (int r = 0; r < 4; ++r)
                red[mslot][nh][hi][r] = part[r];
        }
        __syncthreads();

        // ---- finance epilogue: 32 nodes per block-iteration
        if (tid < 32) {
            const int ms  = tid >> 4;
            const int idx = tid & 15;
            const int tms = (int)(blockIdx.x * 2 + ms) + (tile - (blockIdx.x * 2 + mslot));
            const int   ss   = tms >> 6;
            const int   nn   = ((tms & 63) << 4) + idx;
            const float tt   = (float)ss * kDT;
            const float sp   = (float)nn * kDx;
            const float outv = b3v + red[ms][0][idx >> 2][idx & 3]
                                   + red[ms][1][idx >> 2][idx & 3];

            float delta = -(outv * outv);
            delta *= fminf(expf(-0.01f * delta), 1.0f);          // == 1 (delta<=0), fidelity
            delta *= (1.0f - expf(-kLam * (kTexp - tt))) * kPrincipal;

            const float elt     = expf(-kLam * tt);
            const float account = kPrincipal * sp * expf(-kFee * tt);
            const float fee     = kFee * kDT * account * elt;
            const float payout  = kLam * kDT * fmaxf(kGmdb - account, 0.0f) * elt;

            const float2 v    = make_float2(delta, fee - payout);
            const int    idx4 = ss * kNodes + nn;      // node index
            tab2[2 * idx4] = v;                        // interval nn, .xy
            if (nn > 0) tab2[2 * idx4 - 1] = v;        // interval nn-1, .zw
        }
        __syncthreads();
    }
}

// Block = 256 threads = 4 waves; block owns 64 paths; wave w walks steps
// [15w, 15w+15); per-path pnl reduced across waves via LDS.
__global__ __launch_bounds__(256) void va_main_kernel(
    const float* __restrict__ spots,
    const float4* __restrict__ tab4,   // [kSteps, kNodes] interval pairs
    float* __restrict__ out)
{
    const int lane = threadIdx.x & 63;
    const int wv   = threadIdx.x >> 6;
    const int path = blockIdx.x * 64 + lane;
    const int s0   = wv * 15;

    float pnl  = 0.0f;
    float spot = spots[s0 * kBatch + path];

    #pragma unroll 3
    for (int s = s0; s < s0 + 15; ++s) {
        const float spot_next = spots[(s + 1) * kBatch + path];

        const float x = spot * kInvDx;       // spot > 0 always
        int i = (int)x;
        i = i > kNodes - 2 ? kNodes - 2 : i;
        const float fr = x - (float)i;       // in [0,1) when unclamped

        const float4 c = tab4[s * kNodes + i];
        const float delta  = fmaf(fr, c.z - c.x, c.x);
        const float feepay = fmaf(fr, c.w - c.y, c.y);

        pnl += feepay + delta * (spot_next - spot);
        spot = spot_next;
    }

    __shared__ float red[256];
    red[threadIdx.x] = pnl;
    __syncthreads();

    if (threadIdx.x < 64) {
        out[blockIdx.x * 64 + lane] =
            (red[lane] + red[64 + lane]) + (red[128 + lane] + red[192 + lane]);
    }
}

extern "C" void kernel_launch(void* const* d_in, const int* in_sizes, int n_in,
                              void* d_out, int out_size, void* d_ws, size_t ws_size,
                              hipStream_t stream)
{
    const float* spots = (const float*)d_in[0];
    const float* W1    = (const float*)d_in[1];
    const float* b1    = (const float*)d_in[2];
    const float* W2    = (const float*)d_in[3];
    const float* b2    = (const float*)d_in[4];
    const float* W3    = (const float*)d_in[5];
    const float* b3    = (const float*)d_in[6];
    float* out = (float*)d_out;
    // float4 interval-pair table: 60*1024*16 B = 983 KiB
    float2* tab2 = (float2*)d_ws;
    float4* tab4 = (float4*)d_ws;

    va_build_table<<<kBuildGrid, dim3(256), 0, stream>>>(W1, b1, W2, b2, W3, b3, tab2);
    va_main_kernel<<<kBatch / 64, dim3(256), 0, stream>>>(spots, tab4, out);
}

// Round 9
// 22.015 us; speedup vs baseline: 1.1757x; 1.1757x over previous
//
#include <hip/hip_runtime.h>
#include <math.h>

namespace {
constexpr int kBatch = 65536;
constexpr int kSteps = 60;
constexpr int kNodes = 1024;                 // table nodes per step
constexpr float kInvDx = 64.0f;              // 1 / (16.0/1024)
constexpr float kDx    = 1.0f / 64.0f;

constexpr int kTiles = kSteps * kNodes / 16; // 3840 M-tiles of 16 nodes
constexpr int kBuildGrid = 240;              // 8 tile-iters per wave-chain

constexpr float kDT        = 1.0f / 12.0f;
constexpr float kLam       = 0.01f;
constexpr float kTexp      = 5.0f;
constexpr float kPrincipal = 100.0f;
constexpr float kGmdb      = 100.0f;
constexpr float kFee       = 0.0196f;
}

typedef short short8 __attribute__((ext_vector_type(8)));
typedef float f32x4  __attribute__((ext_vector_type(4)));

// float -> bf16 bits, round-to-nearest-even (finite inputs only)
__device__ inline short f2bf(float f) {
    unsigned u = __builtin_bit_cast(unsigned, f);
    u += 0x7FFFu + ((u >> 16) & 1u);
    return (short)(u >> 16);
}

__device__ inline unsigned short f2h_bits(float f) {
    return __builtin_bit_cast(unsigned short, (_Float16)f);
}
__device__ inline float h2f(unsigned short h) {
    return (float)__builtin_bit_cast(_Float16, h);
}

// MFMA table build (r7 structure).  Block = 256 = 4 waves: wave (mslot, nh).
// Table: per (step, interval i) one PACKED 8B entry = two uints:
//   u[2i]   = half2(delta_i,   feepay_i)
//   u[2i+1] = half2(delta_{i+1}, feepay_{i+1})
// Node (s,n) writes its half2 pair to u[2n] and u[2n-1] -> main does ONE
// aligned 8B gather per step covering both lerp endpoints.
__global__ __launch_bounds__(256) void va_build_table(
    const float* __restrict__ W1,   // [2,128]
    const float* __restrict__ b1,   // [128]
    const float* __restrict__ W2,   // [128,128] row-major (j, o)
    const float* __restrict__ b2,   // [128]
    const float* __restrict__ W3,   // [128]
    const float* __restrict__ b3,   // [1]
    unsigned* __restrict__ tabu)    // [kSteps*kNodes*2] uints
{
    const int tid   = threadIdx.x;
    const int lane  = tid & 63;
    const int lo    = lane & 15;        // A-row / C-col within tile
    const int hi    = lane >> 4;        // k-block selector
    const int wv    = tid >> 6;
    const int mslot = wv >> 1;
    const int nh    = wv & 1;

    // ---- persistent per-wave state: B fragments + b2/W3 for our 64 cols
    short8 bfrag[4][4];                 // [nt][kc]
    float  b2v[4], w3v[4];
    #pragma unroll
    for (int nt = 0; nt < 4; ++nt) {
        const int col = nh * 64 + nt * 16 + lo;
        b2v[nt] = b2[col];
        w3v[nt] = W3[col];
        #pragma unroll
        for (int kc = 0; kc < 4; ++kc) {
            const int kb = kc * 32 + hi * 8;
            short8 bf;
            #pragma unroll
            for (int e = 0; e < 8; ++e)
                bf[e] = f2bf(W2[(kb + e) * 128 + col]);
            bfrag[nt][kc] = bf;
        }
    }
    const float b3v = b3[0];

    __shared__ float red[2][2][16][4];  // [mslot][nh][group][r]

    for (int tile = blockIdx.x * 2 + mslot; tile < kTiles; tile += 2 * gridDim.x) {
        const int   s    = tile >> 6;               // 64 tiles per step
        const int   n0   = (tile & 63) << 4;
        const float t    = (float)s * kDT;
        const float spot = (float)(n0 + lo) * kDx;

        // ---- A fragments: h1 in MFMA A-layout (row=lo, k=kc*32+hi*8+e)
        short8 afrag[4];
        #pragma unroll
        for (int kc = 0; kc < 4; ++kc) {
            const int kb = kc * 32 + hi * 8;
            const f32x4* aw = reinterpret_cast<const f32x4*>(W1 + kb);        // W1[0][k]
            const f32x4* ap = reinterpret_cast<const f32x4*>(W1 + 128 + kb);  // W1[1][k]
            const f32x4* ab = reinterpret_cast<const f32x4*>(b1 + kb);
            const f32x4 a0 = aw[0], a1 = aw[1];
            const f32x4 p0 = ap[0], p1 = ap[1];
            const f32x4 c0 = ab[0], c1 = ab[1];
            short8 af;
            #pragma unroll
            for (int e = 0; e < 4; ++e) {
                float h = fmaxf(fmaf(spot, a0[e], fmaf(t, p0[e], c0[e])), 0.0f);
                af[e] = f2bf(h);
            }
            #pragma unroll
            for (int e = 0; e < 4; ++e) {
                float h = fmaxf(fmaf(spot, a1[e], fmaf(t, p1[e], c1[e])), 0.0f);
                af[4 + e] = f2bf(h);
            }
            afrag[kc] = af;
        }

        // ---- 16 MFMAs: acc[nt] covers C rows 4*hi+r, col nh*64+nt*16+lo
        f32x4 acc[4];
        #pragma unroll
        for (int nt = 0; nt < 4; ++nt) {
            f32x4 a = {b2v[nt], b2v[nt], b2v[nt], b2v[nt]};
            #pragma unroll
            for (int kc = 0; kc < 4; ++kc)
                a = __builtin_amdgcn_mfma_f32_16x16x32_bf16(afrag[kc], bfrag[nt][kc], a, 0, 0, 0);
            acc[nt] = a;
        }

        // ---- relu + W3 dot, butterfly over the 16-lane col group
        float part[4];
        #pragma unroll
        for (int r = 0; r < 4; ++r) {
            float p = 0.0f;
            #pragma unroll
            for (int nt = 0; nt < 4; ++nt)
                p = fmaf(fmaxf(acc[nt][r], 0.0f), w3v[nt], p);
            part[r] = p;
        }
        #pragma unroll
        for (int m = 1; m < 16; m <<= 1) {
            #pragma unroll
            for (int r = 0; r < 4; ++r)
                part[r] += __shfl_xor(part[r], m);
        }
        if (lo == 0) {
            #pragma unroll
            for (int r = 0; r < 4; ++r)
                red[mslot][nh][hi][r] = part[r];
        }
        __syncthreads();

        // ---- finance epilogue: 32 nodes per block-iteration
        if (tid < 32) {
            const int ms  = tid >> 4;
            const int idx = tid & 15;
            const int tms = (int)(blockIdx.x * 2 + ms) + (tile - (blockIdx.x * 2 + mslot));
            const int   ss   = tms >> 6;
            const int   nn   = ((tms & 63) << 4) + idx;
            const float tt   = (float)ss * kDT;
            const float sp   = (float)nn * kDx;
            const float outv = b3v + red[ms][0][idx >> 2][idx & 3]
                                   + red[ms][1][idx >> 2][idx & 3];

            float delta = -(outv * outv);
            delta *= fminf(expf(-0.01f * delta), 1.0f);          // == 1 (delta<=0), fidelity
            delta *= (1.0f - expf(-kLam * (kTexp - tt))) * kPrincipal;

            const float elt     = expf(-kLam * tt);
            const float account = kPrincipal * sp * expf(-kFee * tt);
            const float fee     = kFee * kDT * account * elt;
            const float payout  = kLam * kDT * fmaxf(kGmdb - account, 0.0f) * elt;

            const unsigned pair = (unsigned)f2h_bits(delta)
                                | ((unsigned)f2h_bits(fee - payout) << 16);
            const int idx2 = 2 * (ss * kNodes + nn);
            tabu[idx2] = pair;                       // interval nn, endpoint 0
            if (nn > 0) tabu[idx2 - 1] = pair;       // interval nn-1, endpoint 1
        }
        __syncthreads();
    }
}

// Block = 256 threads = 4 waves; block owns 64 paths; wave w walks steps
// [15w, 15w+15).  All 16 spot values prefetched first (static unroll) so
// the 15 table gathers are independent and fully pipelined.
__global__ __launch_bounds__(256) void va_main_kernel(
    const float* __restrict__ spots,
    const unsigned* __restrict__ tabu,
    float* __restrict__ out)
{
    const int lane = threadIdx.x & 63;
    const int wv   = threadIdx.x >> 6;
    const int path = blockIdx.x * 64 + lane;
    const int s0   = wv * 15;

    float sp[16];
    #pragma unroll
    for (int k = 0; k < 16; ++k)
        sp[k] = spots[(s0 + k) * kBatch + path];

    float pnl = 0.0f;
    #pragma unroll
    for (int k = 0; k < 15; ++k) {
        const float x = sp[k] * kInvDx;      // spot > 0 always
        int i = (int)x;
        i = i > kNodes - 2 ? kNodes - 2 : i;
        const float fr = x - (float)i;

        const uint2 e = *reinterpret_cast<const uint2*>(
            tabu + 2 * ((s0 + k) * kNodes + i));
        const float d0 = h2f((unsigned short)(e.x & 0xFFFFu));
        const float f0 = h2f((unsigned short)(e.x >> 16));
        const float d1 = h2f((unsigned short)(e.y & 0xFFFFu));
        const float f1 = h2f((unsigned short)(e.y >> 16));

        const float delta  = fmaf(fr, d1 - d0, d0);
        const float feepay = fmaf(fr, f1 - f0, f0);
        pnl += feepay + delta * (sp[k + 1] - sp[k]);
    }

    __shared__ float red[256];
    red[threadIdx.x] = pnl;
    __syncthreads();

    if (threadIdx.x < 64) {
        out[blockIdx.x * 64 + lane] =
            (red[lane] + red[64 + lane]) + (red[128 + lane] + red[192 + lane]);
    }
}

extern "C" void kernel_launch(void* const* d_in, const int* in_sizes, int n_in,
                              void* d_out, int out_size, void* d_ws, size_t ws_size,
                              hipStream_t stream)
{
    const float* spots = (const float*)d_in[0];
    const float* W1    = (const float*)d_in[1];
    const float* b1    = (const float*)d_in[2];
    const float* W2    = (const float*)d_in[3];
    const float* b2    = (const float*)d_in[4];
    const float* W3    = (const float*)d_in[5];
    const float* b3    = (const float*)d_in[6];
    float* out = (float*)d_out;
    unsigned* tabu = (unsigned*)d_ws;   // 60*1024*8 B = 492 KiB

    va_build_table<<<kBuildGrid, dim3(256), 0, stream>>>(W1, b1, W2, b2, W3, b3, tabu);
    va_main_kernel<<<kBatch / 64, dim3(256), 0, stream>>>(spots, tabu, out);
}